// Round 14
// baseline (386.000 us; speedup 1.0000x reference)
//
#include <hip/hip_runtime.h>
#include <hip/hip_bf16.h>

// GCN: 3x (GEMM 64x64 -> sym-norm gather via CSR) -> mean-pool -> linear.
// N=100000 nodes, E=1200000 edges, 128 graphs, D=64, classes=10.
// R8: bucketed CSR build + wave-per-node gather (bf16 H'): 362us.
// R9/R11/R12 REVERTED (streamed scatter; pool fusion; shfl-gemm/2-edge gather).
// R13: R8 skeleton + bf16 activations + packed build: 364.8us.
// R14: atomic-free count (per-block hist slices) + scan absorbs init zeroing;
//      gather inner loop 8-wide load batching (2x MLP, deg~12);
//      gemm split accumulator; cnt moved into pool_k run-length flush.

#define N_NODES 100000
#define N_EDGES 1200000
#define N_GRAPHS 128
#define D 64
#define N_CLASSES 10

#define NB 512          // destination buckets
#define BSZ 196         // nodes per bucket (196*512 = 100352 >= N)
#define PEB 4096        // edges per partition block
#define PEB4 (PEB/4)
#define NBP ((N_EDGES + PEB - 1) / PEB)   // 293 partition blocks

typedef unsigned short ushort_t;

__device__ __forceinline__ float bf2f(ushort_t u) {
    union { unsigned int i; float f; } v;
    v.i = ((unsigned int)u) << 16;
    return v.f;
}
__device__ __forceinline__ ushort_t f2bf(float f) {
    __hip_bfloat16 hb = __float2bfloat16(f);
    return *(ushort_t*)&hb;
}

// ---- count: per-block LDS histogram -> private global slice (no atomics) ----
__global__ void count_k(const int4* __restrict__ col4, int* __restrict__ hist, int E4) {
    __shared__ int h[NB];
    for (int i = threadIdx.x; i < NB; i += 256) h[i] = 0;
    __syncthreads();
    int base = blockIdx.x * PEB4;
#pragma unroll
    for (int k = 0; k < 4; ++k) {
        int idx = base + k * 256 + threadIdx.x;
        if (idx < E4) {
            int4 c = col4[idx];
            atomicAdd(&h[c.x / BSZ], 1);
            atomicAdd(&h[c.y / BSZ], 1);
            atomicAdd(&h[c.z / BSZ], 1);
            atomicAdd(&h[c.w / BSZ], 1);
        }
    }
    __syncthreads();
    int* slice = hist + (size_t)blockIdx.x * NB;
    for (int i = threadIdx.x; i < NB; i += 256) slice[i] = h[i];
}

// ---- scan: sum slices -> bcount, exclusive scan -> bstart/bcursor;
//      also zero gsum/cnt (absorbs init_k) ----
__global__ void scan_k(const int* __restrict__ hist, int* __restrict__ bcount,
                       int* __restrict__ bstart, int* __restrict__ bcursor,
                       float* __restrict__ gsum, float* __restrict__ cnt) {
    __shared__ int s[NB];
    int t = threadIdx.x;
    int v0 = 0;
    for (int blk = 0; blk < NBP; ++blk) v0 += hist[(size_t)blk * NB + t];
    bcount[t] = v0;
    s[t] = v0;
    __syncthreads();
    for (int off = 1; off < NB; off <<= 1) {
        int v = (t >= off) ? s[t - off] : 0;
        __syncthreads();
        s[t] += v;
        __syncthreads();
    }
    int ex = s[t] - v0;
    bstart[t] = ex;
    bcursor[t] = ex;
    for (int i = t; i < N_GRAPHS * D; i += NB) gsum[i] = 0.0f;
    if (t < N_GRAPHS) cnt[t] = 0.0f;
}

// ---- scatter edges into bucket-major packed array (src<<8 | dstLocal) ----
__global__ void scatter_k(const int4* __restrict__ row4, const int4* __restrict__ col4,
                          int* __restrict__ bcursor, int* __restrict__ part, int E4) {
    __shared__ int h[NB], gb[NB], c2[NB];
    for (int i = threadIdx.x; i < NB; i += 256) { h[i] = 0; c2[i] = 0; }
    __syncthreads();
    int base = blockIdx.x * PEB4;
    int4 rr[4], cc[4];
    bool ok[4];
#pragma unroll
    for (int k = 0; k < 4; ++k) {
        int idx = base + k * 256 + threadIdx.x;
        ok[k] = idx < E4;
        if (ok[k]) {
            rr[k] = row4[idx];
            cc[k] = col4[idx];
            atomicAdd(&h[cc[k].x / BSZ], 1);
            atomicAdd(&h[cc[k].y / BSZ], 1);
            atomicAdd(&h[cc[k].z / BSZ], 1);
            atomicAdd(&h[cc[k].w / BSZ], 1);
        }
    }
    __syncthreads();
    for (int i = threadIdx.x; i < NB; i += 256)
        if (h[i]) gb[i] = atomicAdd(&bcursor[i], h[i]);
    __syncthreads();
#pragma unroll
    for (int k = 0; k < 4; ++k) {
        if (ok[k]) {
            int r[4] = { rr[k].x, rr[k].y, rr[k].z, rr[k].w };
            int c[4] = { cc[k].x, cc[k].y, cc[k].z, cc[k].w };
#pragma unroll
            for (int j = 0; j < 4; ++j) {
                int bk = c[j] / BSZ;
                int dl = c[j] - bk * BSZ;
                int rk = atomicAdd(&c2[bk], 1);
                part[gb[bk] + rk] = (r[j] << 8) | dl;
            }
        }
    }
}

// ---- per-bucket counting sort by dstLocal: csr + deg/dinv/cursor ----
__global__ void sortbuild_k(const int* __restrict__ part, const int* __restrict__ bstart,
                            const int* __restrict__ bcount, int* __restrict__ csr,
                            int* __restrict__ deg, int* __restrict__ cursor,
                            float* __restrict__ dinv) {
    __shared__ int h[256], st[256], c2[256];
    int b = blockIdx.x, t = threadIdx.x;
    int ebeg = bstart[b];
    int cntE = bcount[b];
    h[t] = 0; c2[t] = 0;
    __syncthreads();
    for (int e = ebeg + t; e < ebeg + cntE; e += 256)
        atomicAdd(&h[part[e] & 255], 1);
    __syncthreads();
    int hv = h[t];
    for (int off = 1; off < 256; off <<= 1) {
        int v = (t >= off) ? h[t - off] : 0;
        __syncthreads();
        h[t] += v;
        __syncthreads();
    }
    st[t] = h[t] - hv;
    __syncthreads();
    int node = b * BSZ + t;
    if (t < BSZ && node < N_NODES) {
        deg[node] = hv;
        dinv[node] = rsqrtf((float)(hv + 1));
        cursor[node] = ebeg + st[t] + hv;   // global segment END
    }
    for (int e = ebeg + t; e < ebeg + cntE; e += 256) {
        int p = part[e];
        int cl = p & 255;
        int rk = atomicAdd(&c2[cl], 1);
        csr[ebeg + st[cl] + rk] = p >> 8;
    }
}

// ---- layer1 GEMM: H'[r] = (X[r] @ W) * dinv[r], X f32 -> H bf16 ----
__global__ __launch_bounds__(256) void gemm_f32_k(
        const float* __restrict__ X, const float* __restrict__ W,
        const float* __restrict__ dinv, ushort_t* __restrict__ H, int n) {
    __shared__ float Xs[4][D];
    int tid = threadIdx.x, wave = tid >> 6, lane = tid & 63;
    float wcol[D];
#pragma unroll
    for (int k = 0; k < D; ++k) wcol[k] = W[k * D + lane];
    for (int row0 = blockIdx.x * 4; row0 < n; row0 += gridDim.x * 4) {
        int row = row0 + wave;
        if (row < n) {
            Xs[wave][lane] = X[(size_t)row * D + lane];
            float a0 = 0.0f, a1 = 0.0f;
#pragma unroll
            for (int k = 0; k < D; k += 2) {
                a0 += Xs[wave][k] * wcol[k];
                a1 += Xs[wave][k + 1] * wcol[k + 1];
            }
            H[(size_t)row * D + lane] = f2bf((a0 + a1) * dinv[row]);
        }
    }
}

// ---- layers2/3 GEMM: H'[r] = (relu(U[r]) @ W) * dinv[r], bf16 -> bf16 ----
__global__ __launch_bounds__(256) void gemm_bf16_k(
        const ushort_t* __restrict__ U, const float* __restrict__ W,
        const float* __restrict__ dinv, ushort_t* __restrict__ H, int n) {
    __shared__ float Xs[4][D];
    int tid = threadIdx.x, wave = tid >> 6, lane = tid & 63;
    float wcol[D];
#pragma unroll
    for (int k = 0; k < D; ++k) wcol[k] = W[k * D + lane];
    for (int row0 = blockIdx.x * 4; row0 < n; row0 += gridDim.x * 4) {
        int row = row0 + wave;
        if (row < n) {
            Xs[wave][lane] = fmaxf(bf2f(U[(size_t)row * D + lane]), 0.0f);
            float a0 = 0.0f, a1 = 0.0f;
#pragma unroll
            for (int k = 0; k < D; k += 2) {
                a0 += Xs[wave][k] * wcol[k];
                a1 += Xs[wave][k + 1] * wcol[k + 1];
            }
            H[(size_t)row * D + lane] = f2bf((a0 + a1) * dinv[row]);
        }
    }
}

// ---- gather: O[c] = bf16( b + dinv[c] * (H'[c] + sum_{r in N(c)} H'[r]) )
//      inner loop batches 8 row-loads before accumulating (MLP) ----
__global__ void gather_k(const ushort_t* __restrict__ Hp, const int* __restrict__ csr,
                         const int* __restrict__ cursor, const int* __restrict__ deg,
                         const float* __restrict__ dinv, const float* __restrict__ b,
                         ushort_t* __restrict__ O, int n) {
    int c = blockIdx.x * 4 + (threadIdx.x >> 6);
    if (c >= n) return;
    int lane = threadIdx.x & 63;
    int end = cursor[c];
    int dg = deg[c];
    float acc = bf2f(Hp[(size_t)c * D + lane]);
    for (int j = end - dg; j < end; j += 64) {
        int idx = j + lane;
        int s = (idx < end) ? csr[idx] : 0;
        int m = min(64, end - j);
        int k = 0;
        for (; k + 8 <= m; k += 8) {
            float v[8];
#pragma unroll
            for (int p = 0; p < 8; ++p) {
                int r = __shfl(s, k + p);
                v[p] = bf2f(Hp[(size_t)r * D + lane]);
            }
            acc += ((v[0] + v[1]) + (v[2] + v[3])) + ((v[4] + v[5]) + (v[6] + v[7]));
        }
        for (; k + 2 <= m; k += 2) {
            int r0 = __shfl(s, k);
            int r1 = __shfl(s, k + 1);
            float v0 = bf2f(Hp[(size_t)r0 * D + lane]);
            float v1 = bf2f(Hp[(size_t)r1 * D + lane]);
            acc += v0 + v1;
        }
        if (k < m) {
            int r0 = __shfl(s, k);
            acc += bf2f(Hp[(size_t)r0 * D + lane]);
        }
    }
    O[(size_t)c * D + lane] = f2bf(b[lane] + dinv[c] * acc);
}

// ---- mean-pool: wave per 64-node chunk (sorted batch run-length), bf16 in;
//      also accumulates per-graph node counts ----
#define POOL_CHUNK 64
__global__ void pool_k(const ushort_t* __restrict__ H, const int* __restrict__ batch,
                       float* __restrict__ gsum, float* __restrict__ cnt, int n) {
    int wid = blockIdx.x * 4 + (threadIdx.x >> 6);
    int lane = threadIdx.x & 63;
    int start = wid * POOL_CHUNK;
    if (start >= n) return;
    int m = min(POOL_CHUNK, n - start);
    int bv = batch[min(start + lane, n - 1)];
    int cur = __shfl(bv, 0);
    float acc = 0.0f;
    int run = 0;
    for (int k = 0; k < m; ++k) {
        int bb = __shfl(bv, k);
        if (bb != cur) {
            atomicAdd(&gsum[cur * D + lane], acc);
            if (lane == 0) atomicAdd(&cnt[cur], (float)run);
            cur = bb; acc = 0.0f; run = 0;
        }
        acc += bf2f(H[(size_t)(start + k) * D + lane]);
        ++run;
    }
    atomicAdd(&gsum[cur * D + lane], acc);
    if (lane == 0) atomicAdd(&cnt[cur], (float)run);
}

// ---- out[b][c] = (gsum[b]/cnt[b]) @ linW + linb ----
__global__ void final_k(const float* __restrict__ gsum, const float* __restrict__ cnt,
                        const float* __restrict__ linW, const float* __restrict__ linb,
                        float* __restrict__ out) {
    int tid = blockIdx.x * 256 + threadIdx.x;
    if (tid >= N_GRAPHS * N_CLASSES) return;
    int b = tid / N_CLASSES, c = tid % N_CLASSES;
    float inv = 1.0f / fmaxf(cnt[b], 1.0f);
    float acc = linb[c];
#pragma unroll
    for (int k = 0; k < D; ++k)
        acc += gsum[b * D + k] * inv * linW[k * N_CLASSES + c];
    out[tid] = acc;
}

extern "C" void kernel_launch(void* const* d_in, const int* in_sizes, int n_in,
                              void* d_out, int out_size, void* d_ws, size_t ws_size,
                              hipStream_t stream) {
    const float* x    = (const float*)d_in[0];
    const int*   ei   = (const int*)  d_in[1];
    const int*   batch= (const int*)  d_in[2];
    const float* W1   = (const float*)d_in[3];
    const float* b1   = (const float*)d_in[4];
    const float* W2   = (const float*)d_in[5];
    const float* b2   = (const float*)d_in[6];
    const float* W3   = (const float*)d_in[7];
    const float* b3   = (const float*)d_in[8];
    const float* linW = (const float*)d_in[9];
    const float* linb = (const float*)d_in[10];
    float* out = (float*)d_out;

    const int N = N_NODES, E = N_EDGES, E4 = N_EDGES / 4;
    const int4* row4 = (const int4*)ei;
    const int4* col4 = (const int4*)(ei + E);

    // workspace layout (4B units), ~37.1MB
    int* wsi = (int*)d_ws;
    float* dinv   = (float*)wsi;                    // 100352
    int*   deg    = wsi + 100352;                   // 100352
    int*   cursor = deg + 100352;                   // 100352
    int*   csr    = cursor + 100352;                // 1200128
    int*   part   = csr + 1200128;                  // 1200128 (packed)
    int*   hist   = part + 1200128;                 // NBP*NB = 150016
    int*   bcount = hist + NBP * NB;                // 512
    int*   bstart = bcount + 512;                   // 512
    int*   bcursor= bstart + 512;                   // 512
    ushort_t* bufH = (ushort_t*)(bcursor + 512);    // N*D bf16 (12.8MB)
    ushort_t* bufA = bufH + (size_t)N * D;          // N*D bf16 (12.8MB)
    float* gsum   = (float*)(bufA + (size_t)N * D); // 8192
    float* cnt    = gsum + N_GRAPHS * D;            // 128

    const int nb_gather= (N + 3) / 4;               // 25000
    const int nb_gemm  = 2048;
    const int nwaves   = (N + POOL_CHUNK - 1) / POOL_CHUNK;
    const int nb_pool  = (nwaves + 3) / 4;

    // bucketed CSR build (atomic-free count)
    count_k<<<NBP, 256, 0, stream>>>(col4, hist, E4);
    scan_k<<<1, NB, 0, stream>>>(hist, bcount, bstart, bcursor, gsum, cnt);
    scatter_k<<<NBP, 256, 0, stream>>>(row4, col4, bcursor, part, E4);
    sortbuild_k<<<NB, 256, 0, stream>>>(part, bstart, bcount, csr, deg, cursor, dinv);

    // layer 1
    gemm_f32_k<<<nb_gemm, 256, 0, stream>>>(x, W1, dinv, bufH, N);
    gather_k<<<nb_gather, 256, 0, stream>>>(bufH, csr, cursor, deg, dinv, b1, bufA, N);
    // layer 2
    gemm_bf16_k<<<nb_gemm, 256, 0, stream>>>(bufA, W2, dinv, bufH, N);
    gather_k<<<nb_gather, 256, 0, stream>>>(bufH, csr, cursor, deg, dinv, b2, bufA, N);
    // layer 3
    gemm_bf16_k<<<nb_gemm, 256, 0, stream>>>(bufA, W3, dinv, bufH, N);
    gather_k<<<nb_gather, 256, 0, stream>>>(bufH, csr, cursor, deg, dinv, b3, bufA, N);

    // pool + classify
    pool_k<<<nb_pool, 256, 0, stream>>>(bufA, batch, gsum, cnt, N);
    final_k<<<(N_GRAPHS * N_CLASSES + 255) / 256, 256, 0, stream>>>(gsum, cnt, linW, linb, out);
}